// Round 3
// baseline (277.852 us; speedup 1.0000x reference)
//
#include <hip/hip_runtime.h>

#define LOG2E 1.44269504088896340736f

typedef __attribute__((ext_vector_type(8))) short short8;
typedef __attribute__((ext_vector_type(4))) float float4v;
typedef __attribute__((ext_vector_type(2))) float float2v;
typedef __attribute__((ext_vector_type(2))) int int2v;

__device__ inline unsigned short f2bf(float f) {
    union { float f; unsigned u; } v; v.f = f;
    unsigned r = v.u + 0x7fffu + ((v.u >> 16) & 1u);
    return (unsigned short)(r >> 16);
}
__device__ inline float bf2f(unsigned short u) {
    union { unsigned u; float f; } v; v.u = ((unsigned)u) << 16;
    return v.f;
}

// ---------------------------------------------------------------------------
// Kernel 0: convert weights to bf16, concatenated Wbf[320][256]
// rows 0-31 = wq, 32-63 = wk, 64-319 = wv.  grid 80 x 256.
// ---------------------------------------------------------------------------
__global__ void wcvt_kernel(const float* __restrict__ wq, const float* __restrict__ wk,
                            const float* __restrict__ wv, unsigned short* __restrict__ Wbf)
{
    int idx = blockIdx.x * 256 + threadIdx.x;     // 20480 float4s
    int e4  = idx * 4;
    int row = e4 >> 8, col = e4 & 255;
    const float* src = (row < 32) ? (wq + row * 256 + col)
                     : (row < 64) ? (wk + (row - 32) * 256 + col)
                                  : (wv + (row - 64) * 256 + col);
    float4v v = *(const float4v*)src;
    int2v p;
    p.x = (unsigned)f2bf(v[0]) | ((unsigned)f2bf(v[1]) << 16);
    p.y = (unsigned)f2bf(v[2]) | ((unsigned)f2bf(v[3]) << 16);
    *(int2v*)(Wbf + e4) = p;
}

// ---------------------------------------------------------------------------
// Kernel 1: projections.  16-pixel i-tiles, grid 1024 (b = blk&3), block 256.
// Q stored (N,32) bf16 PRE-SCALED by cd[i]*log2(e)  (fixed-max softmax fold).
// K stored (N,32) bf16; V stored (C,N) bf16 with per-64 column permutation
// p = (l&15)*4 + (l>>4)  (matches attn P pack order).
// ---------------------------------------------------------------------------
__launch_bounds__(256, 4)
__global__ void proj_kernel(const float* __restrict__ a_p, const float* __restrict__ b_p,
                            const float* __restrict__ c_p,
                            const float* __restrict__ bq, const float* __restrict__ bk,
                            const float* __restrict__ bv,
                            const unsigned short* __restrict__ Wbf,
                            unsigned short* __restrict__ Qg, unsigned short* __restrict__ Kg,
                            unsigned short* __restrict__ Vg)
{
    __shared__ unsigned At[16 * 132];   // a-tile transposed (i, c-pairs) bf16x2
    __shared__ unsigned Bt[16 * 132];

    const int t    = threadIdx.x;
    const int blk  = blockIdx.x;
    const int b    = blk & 3;
    const int t16  = blk >> 2;
    const int i0   = t16 * 16;
    const int lane = t & 63;
    const int w    = t >> 6;
    const int q    = lane >> 4;
    const int n    = lane & 15;

    // ---- stage: each thread loads 2 full c-rows (64B each), packs, transposes ----
    {
        int arr = t >> 7, p = t & 127;
        const float* src = (arr ? b_p : a_p) + ((size_t)(b * 256 + 2 * p)) * 4096 + i0;
        unsigned* dst = arr ? Bt : At;
        float4v r0[4], r1[4];
#pragma unroll
        for (int j4 = 0; j4 < 4; ++j4) r0[j4] = *(const float4v*)(src + j4 * 4);
#pragma unroll
        for (int j4 = 0; j4 < 4; ++j4) r1[j4] = *(const float4v*)(src + 4096 + j4 * 4);
#pragma unroll
        for (int j4 = 0; j4 < 4; ++j4)
#pragma unroll
            for (int jj = 0; jj < 4; ++jj) {
                int i = j4 * 4 + jj;
                dst[i * 132 + p] = (unsigned)f2bf(r0[j4][jj]) | ((unsigned)f2bf(r1[j4][jj]) << 16);
            }
    }
    __syncthreads();

    // ---- GEMM: wave w owns m-tiles {w, w+4, w+8, w+12, w+16} (rows of Wbf) ----
    float4v acc[5];
#pragma unroll
    for (int kk = 0; kk < 5; ++kk) acc[kk] = (float4v){0.f, 0.f, 0.f, 0.f};

#pragma unroll
    for (int kc = 0; kc < 8; ++kc) {
        short8 atf = *(const short8*)((const unsigned short*)At + n * 264 + kc * 32 + q * 8);
        short8 btf = atf;
        if (w >= 2)  // only waves 2,3 own a K m-tile
            btf = *(const short8*)((const unsigned short*)Bt + n * 264 + kc * 32 + q * 8);
#pragma unroll
        for (int kk = 0; kk < 5; ++kk) {
            int mt = w + 4 * kk;
            short8 wf = *(const short8*)(Wbf + (size_t)(mt * 16 + n) * 256 + kc * 32 + q * 8);
            short8 bsel = (mt == 2 || mt == 3) ? btf : atf;
            acc[kk] = __builtin_amdgcn_mfma_f32_16x16x32_bf16(wf, bsel, acc[kk], 0, 0, 0);
        }
    }

    // ---- store (C-layout: row m = mt*16+q*4+r, col i = i0+n) ----
    const int i = i0 + n;
    const int l = i & 63;
    const int pperm = (l & 15) * 4 + (l >> 4);
    // cd for this pixel (down-sampled c), pre-multiplied by log2(e): folded into Q
    const float cdq = c_p[b * 16384 + (i >> 6) * 256 + (i & 63) * 2] * LOG2E;
#pragma unroll
    for (int kk = 0; kk < 5; ++kk) {
        int mt = w + 4 * kk;
#pragma unroll
        for (int r = 0; r < 4; ++r) {
            int mm = mt * 16 + q * 4 + r;
            float bias = (mm < 32) ? bq[mm] : (mm < 64) ? bk[mm - 32] : bv[mm - 64];
            float val = acc[kk][r] + bias;
            if (mm < 32) {
                Qg[(size_t)(b * 4096 + i) * 32 + mm] = f2bf(val * cdq);
            } else if (mm < 64) {
                Kg[(size_t)(b * 4096 + i) * 32 + (mm - 32)] = f2bf(val);
            } else {
                Vg[(size_t)(b * 256 + (mm - 64)) * 4096 + (i >> 6) * 64 + pperm] = f2bf(val);
            }
        }
    }
}

// ---------------------------------------------------------------------------
// Kernel 2: flash attention, split-j, FIXED-MAX softmax (M = 16 in exp2
// domain; logits bounded ~|5|, no overflow/underflow possible).
// grid 1024: b=blk&3, rt=(blk>>2)&63, s=blk>>8.  Block 256 = 4 waves; wave w
// owns S of rows [16w,16w+16) and O of channels [64w,64w+64).
// No running max / alpha / shfl reductions: p = exp2(QK + (-16)), row-sum l
// via MFMA-with-ones.  Writes bf16 partial O + l per row.
// ---------------------------------------------------------------------------
__launch_bounds__(256, 4)
__global__ void attn_kernel(const unsigned short* __restrict__ Qg,
                            const unsigned short* __restrict__ Kg,
                            const unsigned short* __restrict__ Vg,
                            unsigned short* __restrict__ Opart, float* __restrict__ lsum)
{
    __shared__ unsigned short Pt[2][64 * 72];   // P tile (row, 64 permuted cols), bf16

    const int t    = threadIdx.x;
    const int blk  = blockIdx.x;
    const int b    = blk & 3;
    const int rt   = (blk >> 2) & 63;
    const int s    = blk >> 8;
    const int i0   = rt * 64;
    const int jbase = s * 1024;
    const int lane = t & 63;
    const int w    = t >> 6;
    const int q    = lane >> 4;
    const int n    = lane & 15;

    short8 qf = *(const short8*)(Qg + (size_t)(b * 4096 + i0 + 16 * w + n) * 32 + q * 8);

    float4v lacc = (float4v){0.f, 0.f, 0.f, 0.f};
    float4v acc[4][4];
#pragma unroll
    for (int g = 0; g < 4; ++g)
#pragma unroll
        for (int ct = 0; ct < 4; ++ct) acc[g][ct] = (float4v){0.f, 0.f, 0.f, 0.f};

    const float4v m16v = (float4v){-16.f, -16.f, -16.f, -16.f};
    short8 ones;
#pragma unroll
    for (int z = 0; z < 8; ++z) ones[z] = (short)0x3F80;   // bf16 1.0

    const unsigned short* kb = Kg + (size_t)(b * 4096 + jbase + n) * 32 + q * 8;
    const unsigned short* vb = Vg + (size_t)(b * 256 + 64 * w + n) * 4096 + jbase + q * 8;

#pragma unroll 2
    for (int it = 0; it < 16; ++it) {
        const int cur = it & 1;

        // V B-frags for this iter (global, L2-hot) — issue first
        short8 vf[4][2];
#pragma unroll
        for (int ct = 0; ct < 4; ++ct)
#pragma unroll
            for (int kc = 0; kc < 2; ++kc)
                vf[ct][kc] = *(const short8*)(vb + (size_t)ct * 16 * 4096 + it * 64 + kc * 32);
        // K B-frags (global, L1/L2-hot)
        short8 kf[4];
#pragma unroll
        for (int jt = 0; jt < 4; ++jt)
            kf[jt] = *(const short8*)(kb + (size_t)(it * 64 + jt * 16) * 32);

        // S = QK^T - 16  (Q pre-scaled by cd*log2e; -16 folded into acc init)
        float4v sv[4];
#pragma unroll
        for (int jt = 0; jt < 4; ++jt)
            sv[jt] = __builtin_amdgcn_mfma_f32_16x16x32_bf16(qf, kf[jt], m16v, 0, 0, 0);

        // p = exp2(s);  pack to bf16, permuted col order p' = n*4 + jt
        unsigned short* pw = &Pt[cur][(16 * w + q * 4) * 72 + n * 4];
#pragma unroll
        for (int r = 0; r < 4; ++r) {
            float p0 = exp2f(sv[0][r]), p1 = exp2f(sv[1][r]);
            float p2 = exp2f(sv[2][r]), p3 = exp2f(sv[3][r]);
            int2v pd;
            pd.x = (unsigned)f2bf(p0) | ((unsigned)f2bf(p1) << 16);
            pd.y = (unsigned)f2bf(p2) | ((unsigned)f2bf(p3) << 16);
            *(int2v*)(pw + r * 72) = pd;
        }

        __syncthreads();

        // ---- O phase: my c-slice [64w, 64w+64), all 64 rows ----
#pragma unroll
        for (int g = 0; g < 4; ++g) {
            short8 pf0 = *(const short8*)&Pt[cur][(g * 16 + n) * 72 + q * 8];
            short8 pf1 = *(const short8*)&Pt[cur][(g * 16 + n) * 72 + 32 + q * 8];
#pragma unroll
            for (int ct = 0; ct < 4; ++ct) {
                acc[g][ct] = __builtin_amdgcn_mfma_f32_16x16x32_bf16(pf0, vf[ct][0], acc[g][ct], 0, 0, 0);
                acc[g][ct] = __builtin_amdgcn_mfma_f32_16x16x32_bf16(pf1, vf[ct][1], acc[g][ct], 0, 0, 0);
            }
            if (g == w) {   // row-sum l for my rows via ones-MFMA
                lacc = __builtin_amdgcn_mfma_f32_16x16x32_bf16(pf0, ones, lacc, 0, 0, 0);
                lacc = __builtin_amdgcn_mfma_f32_16x16x32_bf16(pf1, ones, lacc, 0, 0, 0);
            }
        }
    }

    // ---- epilogue: partial O (bf16, unnormalized) + l per row ----
    const size_t obase = (size_t)blk * 16384;
#pragma unroll
    for (int g = 0; g < 4; ++g)
#pragma unroll
        for (int ct = 0; ct < 4; ++ct) {
            int c = 64 * w + ct * 16 + n;
            int i = g * 16 + q * 4;
            int2v pk;
            pk.x = (unsigned)f2bf(acc[g][ct][0]) | ((unsigned)f2bf(acc[g][ct][1]) << 16);
            pk.y = (unsigned)f2bf(acc[g][ct][2]) | ((unsigned)f2bf(acc[g][ct][3]) << 16);
            *(int2v*)(Opart + obase + (size_t)c * 64 + i) = pk;
        }
    if (n == 0) {
#pragma unroll
        for (int r = 0; r < 4; ++r)
            lsum[(size_t)blk * 64 + 16 * w + q * 4 + r] = lacc[r];
    }
}

// ---------------------------------------------------------------------------
// Kernel 3: combine 4 splits + residual.  grid 2048: b=blk&3, rt=(blk>>2)&63,
// cs=blk>>8 (8 c-slices of 32).  out = gam*a*cd + (1-cd) * (sum_s O_s)/(sum_s l_s)
// ---------------------------------------------------------------------------
__launch_bounds__(256, 4)
__global__ void combine_kernel(const float* __restrict__ a_p, const float* __restrict__ c_p,
                               const float* __restrict__ gamma_p,
                               const unsigned short* __restrict__ Opart,
                               const float* __restrict__ lsum, float* __restrict__ out)
{
    __shared__ float invL[64];
    __shared__ float cdl[64];

    const int t   = threadIdx.x;
    const int blk = blockIdx.x;
    const int b   = blk & 3;
    const int rt  = (blk >> 2) & 63;
    const int cs  = blk >> 8;
    const int i0  = rt * 64;

    if (t < 64) {
        float L = 0.f;
#pragma unroll
        for (int s = 0; s < 4; ++s)
            L += lsum[(size_t)((s << 8) | (rt << 2) | b) * 64 + t];
        invL[t] = 1.0f / L;
        cdl[t] = c_p[b * 16384 + rt * 256 + 2 * t];
    }
    __syncthreads();

    const float gam = gamma_p[0];
    const int il = (t & 31) * 2;
    const int cq = t >> 5;
#pragma unroll
    for (int k = 0; k < 4; ++k) {
        int c = cs * 32 + cq + 8 * k;
        float o0 = 0.f, o1 = 0.f;
#pragma unroll
        for (int s = 0; s < 4; ++s) {
            int idx = (s << 8) | (rt << 2) | b;
            unsigned pr = *(const unsigned*)(Opart + (size_t)idx * 16384 + (size_t)c * 64 + il);
            o0 += bf2f((unsigned short)(pr & 0xffff));
            o1 += bf2f((unsigned short)(pr >> 16));
        }
        o0 *= invL[il];
        o1 *= invL[il + 1];
        size_t gi = (size_t)(b * 256 + c) * 4096 + i0 + il;
        float2v av = *(const float2v*)(a_p + gi);
        float cd0 = cdl[il], cd1 = cdl[il + 1];
        float2v ov;
        ov[0] = gam * av[0] * cd0 + (1.0f - cd0) * o0;
        ov[1] = gam * av[1] * cd1 + (1.0f - cd1) * o1;
        *(float2v*)(out + gi) = ov;
    }
}

// ---------------------------------------------------------------------------
extern "C" void kernel_launch(void* const* d_in, const int* in_sizes, int n_in,
                              void* d_out, int out_size, void* d_ws, size_t ws_size,
                              hipStream_t stream)
{
    const float* a_p   = (const float*)d_in[0];
    const float* b_p   = (const float*)d_in[1];
    const float* c_p   = (const float*)d_in[2];
    const float* wq    = (const float*)d_in[3];
    const float* bq    = (const float*)d_in[4];
    const float* wk    = (const float*)d_in[5];
    const float* bk    = (const float*)d_in[6];
    const float* wv    = (const float*)d_in[7];
    const float* bv    = (const float*)d_in[8];
    const float* gamma = (const float*)d_in[9];
    float* out = (float*)d_out;

    // workspace layout (ushort elems unless noted):
    // Qg 524288 | Kg 524288 | Vg 4194304 | Wbf 81920 | Opart 16777216 | lsum 65536 f32
    unsigned short* Qg    = (unsigned short*)d_ws;
    unsigned short* Kg    = Qg + (size_t)4 * 4096 * 32;
    unsigned short* Vg    = Kg + (size_t)4 * 4096 * 32;
    unsigned short* Wbf   = Vg + (size_t)4 * 256 * 4096;
    unsigned short* Opart = Wbf + (size_t)320 * 256;
    float*          lsum  = (float*)(Opart + (size_t)1024 * 16384);

    wcvt_kernel<<<80, 256, 0, stream>>>(wq, wk, wv, Wbf);
    proj_kernel<<<1024, 256, 0, stream>>>(a_p, b_p, c_p, bq, bk, bv, Wbf, Qg, Kg, Vg);
    attn_kernel<<<1024, 256, 0, stream>>>(Qg, Kg, Vg, Opart, lsum);
    combine_kernel<<<2048, 256, 0, stream>>>(a_p, c_p, gamma, Opart, lsum, out);
}

// Round 4
// 219.769 us; speedup vs baseline: 1.2643x; 1.2643x over previous
//
#include <hip/hip_runtime.h>

#define LOG2E 1.44269504088896340736f

typedef __attribute__((ext_vector_type(8))) short short8;
typedef __attribute__((ext_vector_type(4))) float float4v;
typedef __attribute__((ext_vector_type(2))) float float2v;
typedef __attribute__((ext_vector_type(2))) int int2v;

__device__ inline unsigned short f2bf(float f) {
    union { float f; unsigned u; } v; v.f = f;
    unsigned r = v.u + 0x7fffu + ((v.u >> 16) & 1u);
    return (unsigned short)(r >> 16);
}
__device__ inline float bf2f(unsigned short u) {
    union { unsigned u; float f; } v; v.u = ((unsigned)u) << 16;
    return v.f;
}

// ---------------------------------------------------------------------------
// Kernel 0: convert weights to bf16, concatenated Wbf[320][256]
// rows 0-31 = wq, 32-63 = wk, 64-319 = wv.  grid 80 x 256.
// ---------------------------------------------------------------------------
__global__ void wcvt_kernel(const float* __restrict__ wq, const float* __restrict__ wk,
                            const float* __restrict__ wv, unsigned short* __restrict__ Wbf)
{
    int idx = blockIdx.x * 256 + threadIdx.x;     // 20480 float4s
    int e4  = idx * 4;
    int row = e4 >> 8, col = e4 & 255;
    const float* src = (row < 32) ? (wq + row * 256 + col)
                     : (row < 64) ? (wk + (row - 32) * 256 + col)
                                  : (wv + (row - 64) * 256 + col);
    float4v v = *(const float4v*)src;
    int2v p;
    p.x = (unsigned)f2bf(v[0]) | ((unsigned)f2bf(v[1]) << 16);
    p.y = (unsigned)f2bf(v[2]) | ((unsigned)f2bf(v[3]) << 16);
    *(int2v*)(Wbf + e4) = p;
}

// ---------------------------------------------------------------------------
// Kernel 1: projections.  16-pixel i-tiles, grid 1024 (b = blk&3), block 256.
// Q stored (N,32) bf16 PRE-SCALED by cd[i]*log2(e)  (fixed-max softmax fold).
// K stored (N,32) bf16; V stored (C,N) bf16 with per-64 column permutation
// p = (l&15)*4 + (l>>4)  (matches attn P pack order).
// ---------------------------------------------------------------------------
__launch_bounds__(256, 3)
__global__ void proj_kernel(const float* __restrict__ a_p, const float* __restrict__ b_p,
                            const float* __restrict__ c_p,
                            const float* __restrict__ bq, const float* __restrict__ bk,
                            const float* __restrict__ bv,
                            const unsigned short* __restrict__ Wbf,
                            unsigned short* __restrict__ Qg, unsigned short* __restrict__ Kg,
                            unsigned short* __restrict__ Vg)
{
    __shared__ unsigned At[16 * 132];   // a-tile transposed (i, c-pairs) bf16x2
    __shared__ unsigned Bt[16 * 132];

    const int t    = threadIdx.x;
    const int blk  = blockIdx.x;
    const int b    = blk & 3;
    const int t16  = blk >> 2;
    const int i0   = t16 * 16;
    const int lane = t & 63;
    const int w    = t >> 6;
    const int q    = lane >> 4;
    const int n    = lane & 15;

    // ---- stage: each thread loads 2 full c-rows (64B each), packs, transposes ----
    {
        int arr = t >> 7, p = t & 127;
        const float* src = (arr ? b_p : a_p) + ((size_t)(b * 256 + 2 * p)) * 4096 + i0;
        unsigned* dst = arr ? Bt : At;
        float4v r0[4], r1[4];
#pragma unroll
        for (int j4 = 0; j4 < 4; ++j4) r0[j4] = *(const float4v*)(src + j4 * 4);
#pragma unroll
        for (int j4 = 0; j4 < 4; ++j4) r1[j4] = *(const float4v*)(src + 4096 + j4 * 4);
#pragma unroll
        for (int j4 = 0; j4 < 4; ++j4)
#pragma unroll
            for (int jj = 0; jj < 4; ++jj) {
                int i = j4 * 4 + jj;
                dst[i * 132 + p] = (unsigned)f2bf(r0[j4][jj]) | ((unsigned)f2bf(r1[j4][jj]) << 16);
            }
    }
    __syncthreads();

    // ---- GEMM: wave w owns m-tiles {w, w+4, w+8, w+12, w+16} (rows of Wbf) ----
    float4v acc[5];
#pragma unroll
    for (int kk = 0; kk < 5; ++kk) acc[kk] = (float4v){0.f, 0.f, 0.f, 0.f};

#pragma unroll
    for (int kc = 0; kc < 8; ++kc) {
        short8 atf = *(const short8*)((const unsigned short*)At + n * 264 + kc * 32 + q * 8);
        short8 btf = atf;
        if (w >= 2)  // only waves 2,3 own a K m-tile
            btf = *(const short8*)((const unsigned short*)Bt + n * 264 + kc * 32 + q * 8);
#pragma unroll
        for (int kk = 0; kk < 5; ++kk) {
            int mt = w + 4 * kk;
            short8 wf = *(const short8*)(Wbf + (size_t)(mt * 16 + n) * 256 + kc * 32 + q * 8);
            short8 bsel = (mt == 2 || mt == 3) ? btf : atf;
            acc[kk] = __builtin_amdgcn_mfma_f32_16x16x32_bf16(wf, bsel, acc[kk], 0, 0, 0);
        }
    }

    // ---- store (C-layout: row m = mt*16+q*4+r, col i = i0+n) ----
    const int i = i0 + n;
    const int l = i & 63;
    const int pperm = (l & 15) * 4 + (l >> 4);
    // cd for this pixel (down-sampled c), pre-multiplied by log2(e): folded into Q
    const float cdq = c_p[b * 16384 + (i >> 6) * 256 + (i & 63) * 2] * LOG2E;
#pragma unroll
    for (int kk = 0; kk < 5; ++kk) {
        int mt = w + 4 * kk;
#pragma unroll
        for (int r = 0; r < 4; ++r) {
            int mm = mt * 16 + q * 4 + r;
            float bias = (mm < 32) ? bq[mm] : (mm < 64) ? bk[mm - 32] : bv[mm - 64];
            float val = acc[kk][r] + bias;
            if (mm < 32) {
                Qg[(size_t)(b * 4096 + i) * 32 + mm] = f2bf(val * cdq);
            } else if (mm < 64) {
                Kg[(size_t)(b * 4096 + i) * 32 + (mm - 32)] = f2bf(val);
            } else {
                Vg[(size_t)(b * 256 + (mm - 64)) * 4096 + (i >> 6) * 64 + pperm] = f2bf(val);
            }
        }
    }
}

// ---------------------------------------------------------------------------
// Kernel 2: flash attention, split-j, FIXED-MAX softmax (M = 16 in exp2
// domain; logits bounded ~|5|, no overflow/underflow possible).
// grid 1024: b=blk&3, rt=(blk>>2)&63, s=blk>>8.  Block 256 = 4 waves; wave w
// owns S of rows [16w,16w+16) and O of channels [64w,64w+64).
// No running max / alpha / shfl reductions: p = exp2(QK + (-16)), row-sum l
// via MFMA-with-ones.  Writes bf16 partial O + l per row.
// NOTE: __launch_bounds__(256,3) — (256,4) caps VGPR at 64 and spills the
// 64-reg accumulator to scratch (R3: +370 MB HBM traffic, 1.3x slower).
// ---------------------------------------------------------------------------
__launch_bounds__(256, 3)
__global__ void attn_kernel(const unsigned short* __restrict__ Qg,
                            const unsigned short* __restrict__ Kg,
                            const unsigned short* __restrict__ Vg,
                            unsigned short* __restrict__ Opart, float* __restrict__ lsum)
{
    __shared__ unsigned short Pt[2][64 * 72];   // P tile (row, 64 permuted cols), bf16

    const int t    = threadIdx.x;
    const int blk  = blockIdx.x;
    const int b    = blk & 3;
    const int rt   = (blk >> 2) & 63;
    const int s    = blk >> 8;
    const int i0   = rt * 64;
    const int jbase = s * 1024;
    const int lane = t & 63;
    const int w    = t >> 6;
    const int q    = lane >> 4;
    const int n    = lane & 15;

    short8 qf = *(const short8*)(Qg + (size_t)(b * 4096 + i0 + 16 * w + n) * 32 + q * 8);

    float4v lacc = (float4v){0.f, 0.f, 0.f, 0.f};
    float4v acc[4][4];
#pragma unroll
    for (int g = 0; g < 4; ++g)
#pragma unroll
        for (int ct = 0; ct < 4; ++ct) acc[g][ct] = (float4v){0.f, 0.f, 0.f, 0.f};

    const float4v m16v = (float4v){-16.f, -16.f, -16.f, -16.f};
    short8 ones;
#pragma unroll
    for (int z = 0; z < 8; ++z) ones[z] = (short)0x3F80;   // bf16 1.0

    const unsigned short* kb = Kg + (size_t)(b * 4096 + jbase + n) * 32 + q * 8;
    const unsigned short* vb = Vg + (size_t)(b * 256 + 64 * w + n) * 4096 + jbase + q * 8;

#pragma unroll 2
    for (int it = 0; it < 16; ++it) {
        const int cur = it & 1;

        // V B-frags for this iter (global, L2-hot) — issue first
        short8 vf[4][2];
#pragma unroll
        for (int ct = 0; ct < 4; ++ct)
#pragma unroll
            for (int kc = 0; kc < 2; ++kc)
                vf[ct][kc] = *(const short8*)(vb + (size_t)ct * 16 * 4096 + it * 64 + kc * 32);
        // K B-frags (global, L1/L2-hot)
        short8 kf[4];
#pragma unroll
        for (int jt = 0; jt < 4; ++jt)
            kf[jt] = *(const short8*)(kb + (size_t)(it * 64 + jt * 16) * 32);

        // S = QK^T - 16  (Q pre-scaled by cd*log2e; -16 folded into acc init)
        float4v sv[4];
#pragma unroll
        for (int jt = 0; jt < 4; ++jt)
            sv[jt] = __builtin_amdgcn_mfma_f32_16x16x32_bf16(qf, kf[jt], m16v, 0, 0, 0);

        // p = exp2(s);  pack to bf16, permuted col order p' = n*4 + jt
        unsigned short* pw = &Pt[cur][(16 * w + q * 4) * 72 + n * 4];
#pragma unroll
        for (int r = 0; r < 4; ++r) {
            float p0 = exp2f(sv[0][r]), p1 = exp2f(sv[1][r]);
            float p2 = exp2f(sv[2][r]), p3 = exp2f(sv[3][r]);
            int2v pd;
            pd.x = (unsigned)f2bf(p0) | ((unsigned)f2bf(p1) << 16);
            pd.y = (unsigned)f2bf(p2) | ((unsigned)f2bf(p3) << 16);
            *(int2v*)(pw + r * 72) = pd;
        }

        __syncthreads();

        // ---- O phase: my c-slice [64w, 64w+64), all 64 rows ----
#pragma unroll
        for (int g = 0; g < 4; ++g) {
            short8 pf0 = *(const short8*)&Pt[cur][(g * 16 + n) * 72 + q * 8];
            short8 pf1 = *(const short8*)&Pt[cur][(g * 16 + n) * 72 + 32 + q * 8];
#pragma unroll
            for (int ct = 0; ct < 4; ++ct) {
                acc[g][ct] = __builtin_amdgcn_mfma_f32_16x16x32_bf16(pf0, vf[ct][0], acc[g][ct], 0, 0, 0);
                acc[g][ct] = __builtin_amdgcn_mfma_f32_16x16x32_bf16(pf1, vf[ct][1], acc[g][ct], 0, 0, 0);
            }
            if (g == w) {   // row-sum l for my rows via ones-MFMA
                lacc = __builtin_amdgcn_mfma_f32_16x16x32_bf16(pf0, ones, lacc, 0, 0, 0);
                lacc = __builtin_amdgcn_mfma_f32_16x16x32_bf16(pf1, ones, lacc, 0, 0, 0);
            }
        }
    }

    // ---- epilogue: partial O (bf16, unnormalized) + l per row ----
    const size_t obase = (size_t)blk * 16384;
#pragma unroll
    for (int g = 0; g < 4; ++g)
#pragma unroll
        for (int ct = 0; ct < 4; ++ct) {
            int c = 64 * w + ct * 16 + n;
            int i = g * 16 + q * 4;
            int2v pk;
            pk.x = (unsigned)f2bf(acc[g][ct][0]) | ((unsigned)f2bf(acc[g][ct][1]) << 16);
            pk.y = (unsigned)f2bf(acc[g][ct][2]) | ((unsigned)f2bf(acc[g][ct][3]) << 16);
            *(int2v*)(Opart + obase + (size_t)c * 64 + i) = pk;
        }
    if (n == 0) {
#pragma unroll
        for (int r = 0; r < 4; ++r)
            lsum[(size_t)blk * 64 + 16 * w + q * 4 + r] = lacc[r];
    }
}

// ---------------------------------------------------------------------------
// Kernel 3: combine 4 splits + residual.  grid 2048: b=blk&3, rt=(blk>>2)&63,
// cs=blk>>8 (8 c-slices of 32).  out = gam*a*cd + (1-cd) * (sum_s O_s)/(sum_s l_s)
// ---------------------------------------------------------------------------
__launch_bounds__(256, 4)
__global__ void combine_kernel(const float* __restrict__ a_p, const float* __restrict__ c_p,
                               const float* __restrict__ gamma_p,
                               const unsigned short* __restrict__ Opart,
                               const float* __restrict__ lsum, float* __restrict__ out)
{
    __shared__ float invL[64];
    __shared__ float cdl[64];

    const int t   = threadIdx.x;
    const int blk = blockIdx.x;
    const int b   = blk & 3;
    const int rt  = (blk >> 2) & 63;
    const int cs  = blk >> 8;
    const int i0  = rt * 64;

    if (t < 64) {
        float L = 0.f;
#pragma unroll
        for (int s = 0; s < 4; ++s)
            L += lsum[(size_t)((s << 8) | (rt << 2) | b) * 64 + t];
        invL[t] = 1.0f / L;
        cdl[t] = c_p[b * 16384 + rt * 256 + 2 * t];
    }
    __syncthreads();

    const float gam = gamma_p[0];
    const int il = (t & 31) * 2;
    const int cq = t >> 5;
#pragma unroll
    for (int k = 0; k < 4; ++k) {
        int c = cs * 32 + cq + 8 * k;
        float o0 = 0.f, o1 = 0.f;
#pragma unroll
        for (int s = 0; s < 4; ++s) {
            int idx = (s << 8) | (rt << 2) | b;
            unsigned pr = *(const unsigned*)(Opart + (size_t)idx * 16384 + (size_t)c * 64 + il);
            o0 += bf2f((unsigned short)(pr & 0xffff));
            o1 += bf2f((unsigned short)(pr >> 16));
        }
        o0 *= invL[il];
        o1 *= invL[il + 1];
        size_t gi = (size_t)(b * 256 + c) * 4096 + i0 + il;
        float2v av = *(const float2v*)(a_p + gi);
        float cd0 = cdl[il], cd1 = cdl[il + 1];
        float2v ov;
        ov[0] = gam * av[0] * cd0 + (1.0f - cd0) * o0;
        ov[1] = gam * av[1] * cd1 + (1.0f - cd1) * o1;
        *(float2v*)(out + gi) = ov;
    }
}

// ---------------------------------------------------------------------------
extern "C" void kernel_launch(void* const* d_in, const int* in_sizes, int n_in,
                              void* d_out, int out_size, void* d_ws, size_t ws_size,
                              hipStream_t stream)
{
    const float* a_p   = (const float*)d_in[0];
    const float* b_p   = (const float*)d_in[1];
    const float* c_p   = (const float*)d_in[2];
    const float* wq    = (const float*)d_in[3];
    const float* bq    = (const float*)d_in[4];
    const float* wk    = (const float*)d_in[5];
    const float* bk    = (const float*)d_in[6];
    const float* wv    = (const float*)d_in[7];
    const float* bv    = (const float*)d_in[8];
    const float* gamma = (const float*)d_in[9];
    float* out = (float*)d_out;

    // workspace layout (ushort elems unless noted):
    // Qg 524288 | Kg 524288 | Vg 4194304 | Wbf 81920 | Opart 16777216 | lsum 65536 f32
    unsigned short* Qg    = (unsigned short*)d_ws;
    unsigned short* Kg    = Qg + (size_t)4 * 4096 * 32;
    unsigned short* Vg    = Kg + (size_t)4 * 4096 * 32;
    unsigned short* Wbf   = Vg + (size_t)4 * 256 * 4096;
    unsigned short* Opart = Wbf + (size_t)320 * 256;
    float*          lsum  = (float*)(Opart + (size_t)1024 * 16384);

    wcvt_kernel<<<80, 256, 0, stream>>>(wq, wk, wv, Wbf);
    proj_kernel<<<1024, 256, 0, stream>>>(a_p, b_p, c_p, bq, bk, bv, Wbf, Qg, Kg, Vg);
    attn_kernel<<<1024, 256, 0, stream>>>(Qg, Kg, Vg, Opart, lsum);
    combine_kernel<<<2048, 256, 0, stream>>>(a_p, c_p, gamma, Opart, lsum, out);
}